// Round 9
// baseline (188.118 us; speedup 1.0000x reference)
//
#include <hip/hip_runtime.h>

// DynamicFilter_79448305041858  (v3: barrier-free rolling-register stencil)
//
// softmax over a size-1 axis == 1.0 -> dynamic filter is all-ones; the op is
// a 3x3 reflect-padded box SUM per (n,c) plane (verified R5/R8, absmax ok):
//   out[y][x] = sum_{dy,dx in {-1,0,1}} in[r(y+dy)][r(x+dx)],  r(-1)=1, r(56)=54
//
// R8 post-mortem: v1 (50us) and v2 (47us) both latency-bound on the
// stage->barrier->compute structure (all pipes <35%; fillBuffer proves
// 6.6 TB/s streaming). v3 removes LDS+barriers: each thread computes a
// 4-wide x 14-row strip with a 3-row rolling register window, loading rows
// directly from global (L1/L2 serve the 3x vertical reuse + edge overlap).

#define HH 56
#define WW 56
#define PLANE (HH * WW)          // 3136 floats
#define STRIPS_PER_PLANE 56      // 14 col-groups x 4 row-strips
#define ROWS_PER_STRIP 14

struct Row { float4 m; float lf, rt; };

__device__ __forceinline__ int refl(int y) {
    return y < 0 ? 1 : (y > HH - 1 ? HH - 2 : y);
}

__device__ __forceinline__ Row load_row(const float* __restrict__ rp, int c, int li, int ri) {
    Row r;
    r.m  = *reinterpret_cast<const float4*>(rp + c);  // 16B aligned (c%4==0, row stride 224B)
    r.lf = rp[li];
    r.rt = rp[ri];
    return r;
}

__global__ __launch_bounds__(256)
void box3x3_reflect_v3(const float* __restrict__ x, float* __restrict__ out, int nthreads) {
    const int t = blockIdx.x * 256 + threadIdx.x;
    if (t >= nthreads) return;

    const int plane = t / STRIPS_PER_PLANE;            // magic-multiply
    const int sub   = t - plane * STRIPS_PER_PLANE;    // 0..55
    const int rs    = sub / 14;                        // row strip 0..3
    const int cg    = sub - rs * 14;                   // col group 0..13
    const int c     = cg * 4;                          // first col of 4
    const int y0    = rs * ROWS_PER_STRIP;

    const int li = (c == 0)      ? 1      : c - 1;     // reflected left col
    const int ri = (c == WW - 4) ? WW - 2 : c + 4;     // reflected right col

    const float* __restrict__ xp = x   + (long long)plane * PLANE;
    float* __restrict__       op = out + (long long)plane * PLANE;

    Row a = load_row(xp + refl(y0 - 1) * WW, c, li, ri);
    Row b = load_row(xp + y0 * WW,           c, li, ri);

    #pragma unroll
    for (int i = 0; i < ROWS_PER_STRIP; ++i) {
        const int y = y0 + i;
        Row d = load_row(xp + refl(y + 1) * WW, c, li, ri);

        float4 v;
        v.x = a.m.x + b.m.x + d.m.x;
        v.y = a.m.y + b.m.y + d.m.y;
        v.z = a.m.z + b.m.z + d.m.z;
        v.w = a.m.w + b.m.w + d.m.w;
        const float lv = a.lf + b.lf + d.lf;
        const float rv = a.rt + b.rt + d.rt;

        float4 o;
        o.x = lv  + v.x + v.y;
        o.y = v.x + v.y + v.z;
        o.z = v.y + v.z + v.w;
        o.w = v.z + v.w + rv;

        *reinterpret_cast<float4*>(op + y * WW + c) = o;

        a = b; b = d;
    }
}

extern "C" void kernel_launch(void* const* d_in, const int* in_sizes, int n_in,
                              void* d_out, int out_size, void* d_ws, size_t ws_size,
                              hipStream_t stream) {
    const float* x = (const float*)d_in[0];   // [16, 384, 56, 56] fp32
    float* out = (float*)d_out;

    const int n_planes = out_size / PLANE;            // 6144
    const int nthreads = n_planes * STRIPS_PER_PLANE; // 344064
    const int n_blocks = (nthreads + 255) / 256;      // 1344
    box3x3_reflect_v3<<<n_blocks, 256, 0, stream>>>(x, out, nthreads);
}

// Round 11
// 173.732 us; speedup vs baseline: 1.0828x; 1.0828x over previous
//
#include <hip/hip_runtime.h>

// DynamicFilter_79448305041858  (v4: thread-per-float4, shuffle halo, no LDS)
//
// softmax over a size-1 axis == 1.0 -> dynamic filter is all-ones; the op is
// a 3x3 reflect-padded box SUM per (n,c) plane (verified R5/R8/R9):
//   out[y][x] = sum_{dy,dx} in[r(y+dy)][r(x+dx)],  r(-1)=1, r(56)=54
//
// R9 post-mortem: v3 (59us) was latency-bound -- 21 waves/CU, 32 VGPRs forced
// serialized dependent loads, scalar edge loads wasted L1 lines. v4 regime:
// max TLP. 16 lanes x 56 rows per plane, 1 float4 out/thread, 3 coalesced
// b128 loads, vertical sum, horizontal halo via width-16 shuffles, reflect
// edges from own lanes (col 1 = v.y, col 54 = v.z). 21504 blocks, no LDS.

#define HH 56
#define WW 56
#define PLANE (HH * WW)     // 3136 floats, 12544 B
#define TPP 896             // threads per plane: 56 rows x 16 lanes (14 active)

typedef float f4 __attribute__((ext_vector_type(4)));

__global__ __launch_bounds__(256)
void box3x3_reflect_v4(const float* __restrict__ x, float* __restrict__ out) {
    const int t = blockIdx.x * 256 + threadIdx.x;   // < 6144*896, exact grid
    const int plane = t / TPP;                       // magic multiply
    const int q = t - plane * TPP;
    const int y   = q >> 4;
    const int sub = q & 15;                          // lane-in-row; 14,15 idle
    const int c   = sub << 2;
    const int cl  = (c > WW - 4) ? WW - 4 : c;       // clamp lanes 14/15 in-bounds

    const int ym = (y == 0)      ? 1      : y - 1;   // reflect rows
    const int yp = (y == HH - 1) ? HH - 2 : y + 1;

    const float* __restrict__ xp = x + (long long)plane * PLANE;

    const f4 a = *reinterpret_cast<const f4*>(xp + ym * WW + cl);
    const f4 b = *reinterpret_cast<const f4*>(xp + y  * WW + cl);
    const f4 d = *reinterpret_cast<const f4*>(xp + yp * WW + cl);

    f4 v = a + b + d;                                // vertical sums

    // Horizontal halo: neighbor lanes within the 16-lane row group.
    const float lf = __shfl_up(v.w, 1, 16);          // col c-1
    const float rt = __shfl_down(v.x, 1, 16);        // col c+4
    const float lv = (sub == 0)  ? v.y : lf;         // reflect col -1 -> 1
    const float rv = (sub == 13) ? v.z : rt;         // reflect col 56 -> 54

    f4 o;
    o.x = lv  + v.x + v.y;
    o.y = v.x + v.y + v.z;
    o.z = v.y + v.z + v.w;
    o.w = v.z + v.w + rv;

    if (sub < 14) {
        f4* dst = reinterpret_cast<f4*>(out + (long long)plane * PLANE + y * WW + c);
        __builtin_nontemporal_store(o, dst);         // don't evict input from L2/L3
    }
}

extern "C" void kernel_launch(void* const* d_in, const int* in_sizes, int n_in,
                              void* d_out, int out_size, void* d_ws, size_t ws_size,
                              hipStream_t stream) {
    const float* x = (const float*)d_in[0];   // [16, 384, 56, 56] fp32
    float* out = (float*)d_out;

    const int n_planes = out_size / PLANE;            // 6144
    const long long nthreads = (long long)n_planes * TPP;  // 5,505,024
    const int n_blocks = (int)(nthreads / 256);       // 21504 (exact)
    box3x3_reflect_v4<<<n_blocks, 256, 0, stream>>>(x, out);
}